// Round 4
// baseline (614.323 us; speedup 1.0000x reference)
//
#include <hip/hip_runtime.h>
#include <math.h>
#include <stdint.h>

#define LOG2_T 19
#define T_SIZE (1u << LOG2_T)
#define T_MASK (T_SIZE - 1u)
#define N_LEVELS 16
#define N_DENSE 8            // levels 0..7 use dense re-laid-out tables
#define N_CELL 5             // levels 0..4: cell tables (8 corners / 32B entry)
#define PRIME1 2654435761u
#define PRIME2 805459861u

typedef unsigned long long u64;
typedef float f4v __attribute__((ext_vector_type(4)));

struct Params {
    int res[N_LEVELS];
    int dOff[N_DENSE];       // dword offset of each dense level table in tabD
    int cellOffC[N_CELL + 1];// cumulative cell counts (levels 0..4)
    int pairOffE[4];         // cumulative pair-entry counts (levels 5..7)
    int cellTot;
    int pairTot;
};

__device__ __forceinline__ float bf_lo(uint32_t v) { return __uint_as_float(v << 16); }
__device__ __forceinline__ float bf_hi(uint32_t v) { return __uint_as_float(v & 0xFFFF0000u); }

__device__ __forceinline__ uint32_t f32_to_bf16_rne(float f) {
    uint32_t u = __float_as_uint(f);
    u += 0x7FFFu + ((u >> 16) & 1u);
    return u >> 16;
}
__device__ __forceinline__ uint32_t pack2(float2 e) {
    return f32_to_bf16_rne(e.x) | (f32_to_bf16_rne(e.y) << 16);
}

__device__ __forceinline__ void nt_store_f2(float2 v, float2* p) {
    union { float2 f; u64 u; } cv; cv.f = v;
    __builtin_nontemporal_store(cv.u, (u64*)p);
}
__device__ __forceinline__ float2 nt_load_f2(const float2* p) {
    union { float2 f; u64 u; } cv;
    cv.u = __builtin_nontemporal_load((const u64*)p);
    return cv.f;
}

// select one dword of a quad by 2-bit index (pure VALU, no dynamic indexing)
__device__ __forceinline__ uint32_t sel4(uint4 q, uint32_t s) {
    const uint32_t a = (s & 1u) ? q.y : q.x;
    const uint32_t b = (s & 1u) ? q.w : q.z;
    return (s & 2u) ? b : a;
}

// ---------- build: fine hash tables (levels 8..15) fp32 -> packed bf16 ----------
__global__ __launch_bounds__(256) void hg_build_fine(
    const float2* __restrict__ emb, uint32_t* __restrict__ tabF)
{
    const int i = blockIdx.x * 256 + threadIdx.x;          // [0, 8*T)
    tabF[i] = pack2(emb[(size_t)N_DENSE * T_SIZE + i]);
}

// ---------- build: cell tables (levels 0..4): 8 corners per cell, 32B ----------
__global__ __launch_bounds__(256) void hg_build_cell(
    const float2* __restrict__ emb, uint32_t* __restrict__ tabD, Params P)
{
    const int i = blockIdx.x * 256 + threadIdx.x;          // one thread per dword
    if (i >= P.cellTot * 8) return;
    const int cg = i >> 3, k = i & 7;                      // cell, corner
    int l = 0;
    while (l < N_CELL - 1 && cg >= P.cellOffC[l + 1]) ++l;
    const int e = cg - P.cellOffC[l];
    const int C = P.res[l] - 1;
    const int ix = e % C; const int r = e / C; const int iy = r % C; const int iz = r / C;
    const uint32_t xx = (uint32_t)(ix + (k & 1));
    const uint32_t yy = (uint32_t)(iy + ((k >> 1) & 1));
    const uint32_t zz = (uint32_t)(iz + (k >> 2));
    const uint32_t h = (xx ^ (yy * PRIME1) ^ (zz * PRIME2)) & T_MASK;
    tabD[P.dOff[l] + e * 8 + k] = pack2(emb[(size_t)l * T_SIZE + h]);
}

// ---------- build: x-pair tables (levels 5..7): (e(x), e(x+1)) per 8B entry ----
__global__ __launch_bounds__(256) void hg_build_pair(
    const float2* __restrict__ emb, uint32_t* __restrict__ tabD, Params P)
{
    const int j = blockIdx.x * 256 + threadIdx.x;          // one thread per entry
    if (j >= P.pairTot) return;
    int lp = 0;
    while (lp < 2 && j >= P.pairOffE[lp + 1]) ++lp;
    const int e = j - P.pairOffE[lp];
    const int l = lp + N_CELL;
    const int R = P.res[l], C = R - 1;
    const int ix = e % C; const int r = e / C; const int yc = r % R; const int zc = r / R;
    const uint32_t m = (((uint32_t)yc) * PRIME1) ^ (((uint32_t)zc) * PRIME2);
    const uint32_t h0 = (((uint32_t)ix)      ^ m) & T_MASK;
    const uint32_t h1 = (((uint32_t)ix + 1u) ^ m) & T_MASK;
    uint2 v;
    v.x = pack2(emb[(size_t)l * T_SIZE + h0]);
    v.y = pack2(emb[(size_t)l * T_SIZE + h1]);
    *(uint2*)(tabD + P.dOff[l] + (size_t)e * 2) = v;
}

// ---------- gather helpers ----------
struct Pt { int ix, iy, iz; float fx, fy, fz; };

__device__ __forceinline__ Pt mk_pt(float x0, float x1, float x2,
                                    int rl, float rf) {
    Pt p;
    const float sx = x0 * rf, sy = x1 * rf, sz = x2 * rf;
    int ix = (int)sx; ix = ix < 0 ? 0 : (ix > rl - 2 ? rl - 2 : ix);
    int iy = (int)sy; iy = iy < 0 ? 0 : (iy > rl - 2 ? rl - 2 : iy);
    int iz = (int)sz; iz = iz < 0 ? 0 : (iz > rl - 2 ? rl - 2 : iz);
    p.ix = ix; p.iy = iy; p.iz = iz;
    p.fx = sx - (float)ix; p.fy = sy - (float)iy; p.fz = sz - (float)iz;
    return p;
}

__device__ __forceinline__ float2 blend8s(
    uint32_t c0, uint32_t c1, uint32_t c2, uint32_t c3,
    uint32_t c4, uint32_t c5, uint32_t c6, uint32_t c7,
    float fx, float fy, float fz)
{
    const float wx0 = 1.0f - fx, wx1 = fx;
    const float wy0 = 1.0f - fy, wy1 = fy;
    const float wz0 = 1.0f - fz, wz1 = fz;
    float w, f0 = 0.0f, f1 = 0.0f;
    w = wx0 * wy0 * wz0; f0 = fmaf(w, bf_lo(c0), f0); f1 = fmaf(w, bf_hi(c0), f1);
    w = wx1 * wy0 * wz0; f0 = fmaf(w, bf_lo(c1), f0); f1 = fmaf(w, bf_hi(c1), f1);
    w = wx0 * wy1 * wz0; f0 = fmaf(w, bf_lo(c2), f0); f1 = fmaf(w, bf_hi(c2), f1);
    w = wx1 * wy1 * wz0; f0 = fmaf(w, bf_lo(c3), f0); f1 = fmaf(w, bf_hi(c3), f1);
    w = wx0 * wy0 * wz1; f0 = fmaf(w, bf_lo(c4), f0); f1 = fmaf(w, bf_hi(c4), f1);
    w = wx1 * wy0 * wz1; f0 = fmaf(w, bf_lo(c5), f0); f1 = fmaf(w, bf_hi(c5), f1);
    w = wx0 * wy1 * wz1; f0 = fmaf(w, bf_lo(c6), f0); f1 = fmaf(w, bf_hi(c6), f1);
    w = wx1 * wy1 * wz1; f0 = fmaf(w, bf_lo(c7), f0); f1 = fmaf(w, bf_hi(c7), f1);
    float2 o; o.x = f0; o.y = f1;
    return o;
}

// ---------- phase 1: gather + trilinear blend, level-major output ----------
// Thread = 2 ADJACENT points (2t, 2t+1) x 2 levels (dense l, fine l+8).
// Request-count engineering (the kernel is L2 scattered-request bound):
//   fine:  1 aligned dwordx4 per (dy,dz) combo covers both x-corners when
//          ix%4 != 3 (h(x+1) = h(x) ^ (x^(x+1)), same 16B quad) -> avg 5 req
//   dense l<5:  cell table, 2x dwordx4 = 2 req (was avg 5.5)
//   dense 5..7: x-pair table, 4x 8B = 4 req
//   x: 3 coalesced dwordx2 per 2 points; feat: one 16B store per row.
__global__ __launch_bounds__(256, 4) void hg_levels(
    const float* __restrict__ x,
    const uint32_t* __restrict__ tabF,   // [8, T] packed bf16x2 (levels 8..15)
    const uint32_t* __restrict__ tabD,   // dense cell/pair tables (levels 0..7)
    float2* __restrict__ feat,           // [16, N]
    int N, Params P)
{
    const int l  = blockIdx.x & 7;           // dense level; fine level = l+8
    const int lf = l + 8;
    const int tt = (blockIdx.x >> 3) * 256 + threadIdx.x;
    const int n0 = tt * 2;
    if (n0 >= N) return;
    const int n1 = n0 + 1;
    const bool hasB = (n1 < N);

    float ax, ay, az, bx, by, bz;
    const float* xb = x + (size_t)n0 * 3;
    if (hasB) {
        const float2 u0 = *(const float2*)(xb);
        const float2 u1 = *(const float2*)(xb + 2);
        const float2 u2 = *(const float2*)(xb + 4);
        ax = u0.x; ay = u0.y; az = u1.x; bx = u1.y; by = u2.x; bz = u2.y;
    } else {
        ax = xb[0]; ay = xb[1]; az = xb[2]; bx = ax; by = ay; bz = az;
    }

    const int rd = P.res[l];  const float rdf = (float)(rd - 1);
    const int rf = P.res[lf]; const float rff = (float)(rf - 1);

    const Pt fA = mk_pt(ax, ay, az, rf, rff);
    const Pt fB = mk_pt(bx, by, bz, rf, rff);
    const Pt dA = mk_pt(ax, ay, az, rd, rdf);
    const Pt dB = mk_pt(bx, by, bz, rd, rdf);

    // ---- fine gathers: 4 quads per point ----
    const uint32_t* __restrict__ tf = tabF + (size_t)l * T_SIZE;

    const uint32_t hxA = (uint32_t)fA.ix;
    const uint32_t dxA = hxA ^ (hxA + 1u);
    const uint32_t yA0 = (uint32_t)fA.iy * PRIME1, yA1 = yA0 + PRIME1;
    const uint32_t zA0 = (uint32_t)fA.iz * PRIME2, zA1 = zA0 + PRIME2;
    const uint32_t iA00 = (hxA ^ yA0 ^ zA0) & T_MASK;
    const uint32_t iA10 = (hxA ^ yA1 ^ zA0) & T_MASK;
    const uint32_t iA01 = (hxA ^ yA0 ^ zA1) & T_MASK;
    const uint32_t iA11 = (hxA ^ yA1 ^ zA1) & T_MASK;
    const uint4 qA00 = *(const uint4*)(tf + (iA00 & ~3u));
    const uint4 qA10 = *(const uint4*)(tf + (iA10 & ~3u));
    const uint4 qA01 = *(const uint4*)(tf + (iA01 & ~3u));
    const uint4 qA11 = *(const uint4*)(tf + (iA11 & ~3u));

    const uint32_t hxB = (uint32_t)fB.ix;
    const uint32_t dxB = hxB ^ (hxB + 1u);
    const uint32_t yB0 = (uint32_t)fB.iy * PRIME1, yB1 = yB0 + PRIME1;
    const uint32_t zB0 = (uint32_t)fB.iz * PRIME2, zB1 = zB0 + PRIME2;
    const uint32_t iB00 = (hxB ^ yB0 ^ zB0) & T_MASK;
    const uint32_t iB10 = (hxB ^ yB1 ^ zB0) & T_MASK;
    const uint32_t iB01 = (hxB ^ yB0 ^ zB1) & T_MASK;
    const uint32_t iB11 = (hxB ^ yB1 ^ zB1) & T_MASK;
    const uint4 qB00 = *(const uint4*)(tf + (iB00 & ~3u));
    const uint4 qB10 = *(const uint4*)(tf + (iB10 & ~3u));
    const uint4 qB01 = *(const uint4*)(tf + (iB01 & ~3u));
    const uint4 qB11 = *(const uint4*)(tf + (iB11 & ~3u));

    // rare second x-corner loads (ix%4 == 3: quad doesn't cover ix+1)
    uint32_t eA1 = 0, eA3 = 0, eA5 = 0, eA7 = 0;
    const bool exA = dxA >= 4u;
    if (exA) {
        eA1 = tf[(iA00 ^ dxA) & T_MASK];
        eA3 = tf[(iA10 ^ dxA) & T_MASK];
        eA5 = tf[(iA01 ^ dxA) & T_MASK];
        eA7 = tf[(iA11 ^ dxA) & T_MASK];
    }
    uint32_t eB1 = 0, eB3 = 0, eB5 = 0, eB7 = 0;
    const bool exB = dxB >= 4u;
    if (exB) {
        eB1 = tf[(iB00 ^ dxB) & T_MASK];
        eB3 = tf[(iB10 ^ dxB) & T_MASK];
        eB5 = tf[(iB01 ^ dxB) & T_MASK];
        eB7 = tf[(iB11 ^ dxB) & T_MASK];
    }

    // ---- dense gathers ----
    uint32_t a0, a1, a2, a3, a4, a5, a6, a7;
    uint32_t b0, b1, b2, b3, b4, b5, b6, b7;
    if (l < N_CELL) {
        const int C = rd - 1;
        const uint32_t* cbA = tabD + P.dOff[l] + (size_t)((dA.iz * C + dA.iy) * C + dA.ix) * 8;
        const uint4 qa0 = *(const uint4*)cbA;
        const uint4 qa1 = *(const uint4*)(cbA + 4);
        const uint32_t* cbB = tabD + P.dOff[l] + (size_t)((dB.iz * C + dB.iy) * C + dB.ix) * 8;
        const uint4 qb0 = *(const uint4*)cbB;
        const uint4 qb1 = *(const uint4*)(cbB + 4);
        a0 = qa0.x; a1 = qa0.y; a2 = qa0.z; a3 = qa0.w;
        a4 = qa1.x; a5 = qa1.y; a6 = qa1.z; a7 = qa1.w;
        b0 = qb0.x; b1 = qb0.y; b2 = qb0.z; b3 = qb0.w;
        b4 = qb1.x; b5 = qb1.y; b6 = qb1.z; b7 = qb1.w;
    } else {
        const int R = rd, C = rd - 1;
        const uint32_t* pb = tabD + P.dOff[l];
        const int rA0 = (dA.iz * R + dA.iy) * C + dA.ix;
        const int rA1 = rA0 + C;            // dy=1
        const int rA2 = rA0 + R * C;        // dz=1
        const int rA3 = rA2 + C;
        const uint2 pA0 = *(const uint2*)(pb + (size_t)rA0 * 2);
        const uint2 pA1 = *(const uint2*)(pb + (size_t)rA1 * 2);
        const uint2 pA2 = *(const uint2*)(pb + (size_t)rA2 * 2);
        const uint2 pA3 = *(const uint2*)(pb + (size_t)rA3 * 2);
        const int rB0 = (dB.iz * R + dB.iy) * C + dB.ix;
        const int rB1 = rB0 + C;
        const int rB2 = rB0 + R * C;
        const int rB3 = rB2 + C;
        const uint2 pB0 = *(const uint2*)(pb + (size_t)rB0 * 2);
        const uint2 pB1 = *(const uint2*)(pb + (size_t)rB1 * 2);
        const uint2 pB2 = *(const uint2*)(pb + (size_t)rB2 * 2);
        const uint2 pB3 = *(const uint2*)(pb + (size_t)rB3 * 2);
        a0 = pA0.x; a1 = pA0.y; a2 = pA1.x; a3 = pA1.y;
        a4 = pA2.x; a5 = pA2.y; a6 = pA3.x; a7 = pA3.y;
        b0 = pB0.x; b1 = pB0.y; b2 = pB1.x; b3 = pB1.y;
        b4 = pB2.x; b5 = pB2.y; b6 = pB3.x; b7 = pB3.y;
    }

    __builtin_amdgcn_sched_barrier(0);

    // fine corner extraction (VALU selects, no memory)
    const uint32_t fA0 = sel4(qA00, iA00 & 3u);
    const uint32_t fA1 = exA ? eA1 : sel4(qA00, (iA00 ^ dxA) & 3u);
    const uint32_t fA2 = sel4(qA10, iA10 & 3u);
    const uint32_t fA3 = exA ? eA3 : sel4(qA10, (iA10 ^ dxA) & 3u);
    const uint32_t fA4 = sel4(qA01, iA01 & 3u);
    const uint32_t fA5 = exA ? eA5 : sel4(qA01, (iA01 ^ dxA) & 3u);
    const uint32_t fA6 = sel4(qA11, iA11 & 3u);
    const uint32_t fA7 = exA ? eA7 : sel4(qA11, (iA11 ^ dxA) & 3u);

    const uint32_t fB0 = sel4(qB00, iB00 & 3u);
    const uint32_t fB1 = exB ? eB1 : sel4(qB00, (iB00 ^ dxB) & 3u);
    const uint32_t fB2 = sel4(qB10, iB10 & 3u);
    const uint32_t fB3 = exB ? eB3 : sel4(qB10, (iB10 ^ dxB) & 3u);
    const uint32_t fB4 = sel4(qB01, iB01 & 3u);
    const uint32_t fB5 = exB ? eB5 : sel4(qB01, (iB01 ^ dxB) & 3u);
    const uint32_t fB6 = sel4(qB11, iB11 & 3u);
    const uint32_t fB7 = exB ? eB7 : sel4(qB11, (iB11 ^ dxB) & 3u);

    const float2 oFA = blend8s(fA0, fA1, fA2, fA3, fA4, fA5, fA6, fA7, fA.fx, fA.fy, fA.fz);
    const float2 oFB = blend8s(fB0, fB1, fB2, fB3, fB4, fB5, fB6, fB7, fB.fx, fB.fy, fB.fz);
    const float2 oDA = blend8s(a0, a1, a2, a3, a4, a5, a6, a7, dA.fx, dA.fy, dA.fz);
    const float2 oDB = blend8s(b0, b1, b2, b3, b4, b5, b6, b7, dB.fx, dB.fy, dB.fz);

    if (hasB) {
        f4v oD; oD.x = oDA.x; oD.y = oDA.y; oD.z = oDB.x; oD.w = oDB.y;
        __builtin_nontemporal_store(oD, (f4v*)&feat[(size_t)l * N + n0]);
        f4v oF; oF.x = oFA.x; oF.y = oFA.y; oF.z = oFB.x; oF.w = oFB.y;
        __builtin_nontemporal_store(oF, (f4v*)&feat[(size_t)lf * N + n0]);
    } else {
        nt_store_f2(oDA, &feat[(size_t)l  * N + n0]);
        nt_store_f2(oFA, &feat[(size_t)lf * N + n0]);
    }
}

// ---------- phase 2: LDS-tiled transpose [16,N] -> [N,16] float2 ----------
__global__ __launch_bounds__(256) void hg_transpose(
    const float2* __restrict__ feat, f4v* __restrict__ out, int N)
{
    __shared__ float2 st[N_LEVELS][33];
    const int base = blockIdx.x * 32;
    const int t = threadIdx.x;
#pragma unroll
    for (int i = 0; i < 2; ++i) {
        const int idx = i * 256 + t;       // 0..511
        const int l = idx >> 5, p = idx & 31;
        const int n = base + p;
        st[l][p] = (n < N) ? nt_load_f2(&feat[(size_t)l * N + n]) : make_float2(0.f, 0.f);
    }
    __syncthreads();
    const int p = t >> 3, k = t & 7;
    const int n = base + p;
    if (n < N) {
        const float2 a = st[2 * k][p], b = st[2 * k + 1][p];
        f4v o; o.x = a.x; o.y = a.y; o.z = b.x; o.w = b.y;
        __builtin_nontemporal_store(o, &out[(size_t)n * 8 + k]);
    }
}

// ---------- fallback: used only if ws is too small ----------
__global__ __launch_bounds__(256) void hg_fallback(
    const float* __restrict__ x, const float* __restrict__ emb,
    float* __restrict__ out, int N, Params P)
{
    const int gid = blockIdx.x * 256 + threadIdx.x;
    const int n = gid >> 4, l = gid & 15;
    if (n >= N) return;
    const int rl = P.res[l];
    const float rf = (float)(rl - 1);
    float sx = x[n * 3 + 0] * rf, sy = x[n * 3 + 1] * rf, sz = x[n * 3 + 2] * rf;
    int ix = (int)sx; ix = ix < 0 ? 0 : (ix > rl - 2 ? rl - 2 : ix);
    int iy = (int)sy; iy = iy < 0 ? 0 : (iy > rl - 2 ? rl - 2 : iy);
    int iz = (int)sz; iz = iz < 0 ? 0 : (iz > rl - 2 ? rl - 2 : iz);
    const float fx = sx - ix, fy = sy - iy, fz = sz - iz;
    const uint32_t hx0 = (uint32_t)ix, hx1 = hx0 + 1u;
    const uint32_t hy0 = (uint32_t)iy * PRIME1, hy1 = hy0 + PRIME1;
    const uint32_t hz0 = (uint32_t)iz * PRIME2, hz1 = hz0 + PRIME2;
    const float2* tab = (const float2*)emb + (size_t)l * T_SIZE;
    float2 e0 = tab[(hx0 ^ hy0 ^ hz0) & T_MASK], e1 = tab[(hx1 ^ hy0 ^ hz0) & T_MASK];
    float2 e2 = tab[(hx0 ^ hy1 ^ hz0) & T_MASK], e3 = tab[(hx1 ^ hy1 ^ hz0) & T_MASK];
    float2 e4 = tab[(hx0 ^ hy0 ^ hz1) & T_MASK], e5 = tab[(hx1 ^ hy0 ^ hz1) & T_MASK];
    float2 e6 = tab[(hx0 ^ hy1 ^ hz1) & T_MASK], e7 = tab[(hx1 ^ hy1 ^ hz1) & T_MASK];
    const float wx0 = 1.0f - fx, wx1 = fx, wy0 = 1.0f - fy, wy1 = fy, wz0 = 1.0f - fz, wz1 = fz;
    float w, f0 = 0.0f, f1 = 0.0f;
    w = wx0 * wy0 * wz0; f0 = fmaf(w, e0.x, f0); f1 = fmaf(w, e0.y, f1);
    w = wx1 * wy0 * wz0; f0 = fmaf(w, e1.x, f0); f1 = fmaf(w, e1.y, f1);
    w = wx0 * wy1 * wz0; f0 = fmaf(w, e2.x, f0); f1 = fmaf(w, e2.y, f1);
    w = wx1 * wy1 * wz0; f0 = fmaf(w, e3.x, f0); f1 = fmaf(w, e3.y, f1);
    w = wx0 * wy0 * wz1; f0 = fmaf(w, e4.x, f0); f1 = fmaf(w, e4.y, f1);
    w = wx1 * wy0 * wz1; f0 = fmaf(w, e5.x, f0); f1 = fmaf(w, e5.y, f1);
    w = wx0 * wy1 * wz1; f0 = fmaf(w, e6.x, f0); f1 = fmaf(w, e6.y, f1);
    w = wx1 * wy1 * wz1; f0 = fmaf(w, e7.x, f0); f1 = fmaf(w, e7.y, f1);
    float2 o; o.x = f0; o.y = f1;
    ((float2*)out)[(size_t)n * N_LEVELS + l] = o;
}

extern "C" void kernel_launch(void* const* d_in, const int* in_sizes, int n_in,
                              void* d_out, int out_size, void* d_ws, size_t ws_size,
                              hipStream_t stream) {
    const float* x   = (const float*)d_in[0];
    const float* emb = (const float*)d_in[1];
    const int N = in_sizes[0] / 3;

    // CPython-identical level resolutions (truncation-sensitive: 16*b^3 == 32)
    Params P;
    const double b = exp((log(512.0) - log(16.0)) / 15.0);
    for (int i = 0; i < N_LEVELS; ++i)
        P.res[i] = (int)(16.0 * pow(b, (double)i));

    // cell tables (levels 0..4)
    P.cellOffC[0] = 0;
    for (int l = 0; l < N_CELL; ++l) {
        const int C = P.res[l] - 1;
        P.cellOffC[l + 1] = P.cellOffC[l] + C * C * C;
    }
    P.cellTot = P.cellOffC[N_CELL];
    // pair tables (levels 5..7)
    P.pairOffE[0] = 0;
    for (int lp = 0; lp < 3; ++lp) {
        const int R = P.res[N_CELL + lp], C = R - 1;
        P.pairOffE[lp + 1] = P.pairOffE[lp] + C * R * R;
    }
    P.pairTot = P.pairOffE[3];
    // dword offsets in tabD
    for (int l = 0; l < N_CELL; ++l) P.dOff[l] = P.cellOffC[l] * 8;
    for (int lp = 0; lp < 3; ++lp)  P.dOff[N_CELL + lp] = P.cellTot * 8 + P.pairOffE[lp] * 2;
    const size_t dense_dwords = (size_t)P.cellTot * 8 + (size_t)P.pairTot * 2;

    const size_t fine_bytes  = (size_t)N_DENSE * T_SIZE * sizeof(uint32_t);       // 16 MB
    const size_t dense_bytes = (dense_dwords * sizeof(uint32_t) + 255) & ~255ull; // ~10.9 MB
    const size_t feat_bytes  = (size_t)N_LEVELS * N * sizeof(float2);             // 128 MB

    if (ws_size >= fine_bytes + dense_bytes + feat_bytes) {
        uint32_t* tabF = (uint32_t*)d_ws;
        uint32_t* tabD = (uint32_t*)((char*)d_ws + fine_bytes);
        float2*   feat = (float2*)((char*)d_ws + fine_bytes + dense_bytes);

        hipLaunchKernelGGL(hg_build_fine, dim3(N_DENSE * T_SIZE / 256), dim3(256), 0, stream,
                           (const float2*)emb, tabF);
        hipLaunchKernelGGL(hg_build_cell, dim3((P.cellTot * 8 + 255) / 256), dim3(256), 0, stream,
                           (const float2*)emb, tabD, P);
        hipLaunchKernelGGL(hg_build_pair, dim3((P.pairTot + 255) / 256), dim3(256), 0, stream,
                           (const float2*)emb, tabD, P);

        const int chunks = (N + 511) / 512;    // 512 points per block (2/thread)
        hipLaunchKernelGGL(hg_levels, dim3(chunks * 8), dim3(256), 0, stream,
                           x, tabF, tabD, feat, N, P);

        hipLaunchKernelGGL(hg_transpose, dim3((N + 31) / 32), dim3(256), 0, stream,
                           feat, (f4v*)d_out, N);
    } else {
        hipLaunchKernelGGL(hg_fallback, dim3((N * 16 + 255) / 256), dim3(256), 0, stream,
                           x, emb, (float*)d_out, N, P);
    }
}

// Round 5
// 548.345 us; speedup vs baseline: 1.1203x; 1.1203x over previous
//
#include <hip/hip_runtime.h>
#include <math.h>
#include <stdint.h>

#define LOG2_T 19
#define T_SIZE (1u << LOG2_T)
#define T_MASK (T_SIZE - 1u)
#define N_LEVELS 16
#define N_CELL 5             // levels 0..4: cell tables (8 corners / 32B entry)
#define N_HASH 11            // levels 5..15: packed bf16 hash tables in tabF
#define PRIME1 2654435761u
#define PRIME2 805459861u

typedef unsigned long long u64;
typedef float f4v __attribute__((ext_vector_type(4)));

struct Params {
    int res[N_LEVELS];
    int dOff[N_CELL];        // dword offset of each cell-table level in tabD
    int cellOffC[N_CELL + 1];// cumulative cell counts (levels 0..4)
    int cellTot;
};

__device__ __forceinline__ float bf_lo(uint32_t v) { return __uint_as_float(v << 16); }
__device__ __forceinline__ float bf_hi(uint32_t v) { return __uint_as_float(v & 0xFFFF0000u); }

__device__ __forceinline__ uint32_t f32_to_bf16_rne(float f) {
    uint32_t u = __float_as_uint(f);
    u += 0x7FFFu + ((u >> 16) & 1u);
    return u >> 16;
}
__device__ __forceinline__ uint32_t pack2(float2 e) {
    return f32_to_bf16_rne(e.x) | (f32_to_bf16_rne(e.y) << 16);
}

__device__ __forceinline__ float2 nt_load_f2(const float2* p) {
    union { float2 f; u64 u; } cv;
    cv.u = __builtin_nontemporal_load((const u64*)p);
    return cv.f;
}
__device__ __forceinline__ void nt_store_f2(float2 v, float2* p) {
    union { float2 f; u64 u; } cv; cv.f = v;
    __builtin_nontemporal_store(cv.u, (u64*)p);
}

// select one dword of a quad by 2-bit index (pure VALU, no dynamic indexing)
__device__ __forceinline__ uint32_t sel4(uint4 q, uint32_t s) {
    const uint32_t a = (s & 1u) ? q.y : q.x;
    const uint32_t b = (s & 1u) ? q.w : q.z;
    return (s & 2u) ? b : a;
}

// ---------- build: hash tables (levels 5..15) fp32 -> packed bf16 ----------
__global__ __launch_bounds__(256) void hg_build_fine(
    const float2* __restrict__ emb, uint32_t* __restrict__ tabF)
{
    const int i = blockIdx.x * 256 + threadIdx.x;          // [0, N_HASH*T)
    tabF[i] = pack2(emb[(size_t)N_CELL * T_SIZE + i]);
}

// ---------- build: cell tables (levels 0..4): 8 corners per cell, 32B ----------
__global__ __launch_bounds__(256) void hg_build_cell(
    const float2* __restrict__ emb, uint32_t* __restrict__ tabD, Params P)
{
    const int i = blockIdx.x * 256 + threadIdx.x;          // one thread per dword
    if (i >= P.cellTot * 8) return;
    const int cg = i >> 3, k = i & 7;                      // cell, corner
    int l = 0;
    while (l < N_CELL - 1 && cg >= P.cellOffC[l + 1]) ++l;
    const int e = cg - P.cellOffC[l];
    const int C = P.res[l] - 1;
    const int ix = e % C; const int r = e / C; const int iy = r % C; const int iz = r / C;
    const uint32_t xx = (uint32_t)(ix + (k & 1));
    const uint32_t yy = (uint32_t)(iy + ((k >> 1) & 1));
    const uint32_t zz = (uint32_t)(iz + (k >> 2));
    const uint32_t h = (xx ^ (yy * PRIME1) ^ (zz * PRIME2)) & T_MASK;
    tabD[P.dOff[l] + e * 8 + k] = pack2(emb[(size_t)l * T_SIZE + h]);
}

// ---------- gather helpers ----------
struct Pt { int ix, iy, iz; float fx, fy, fz; };

__device__ __forceinline__ Pt mk_pt(float x0, float x1, float x2,
                                    int rl, float rf) {
    Pt p;
    const float sx = x0 * rf, sy = x1 * rf, sz = x2 * rf;
    int ix = (int)sx; ix = ix < 0 ? 0 : (ix > rl - 2 ? rl - 2 : ix);
    int iy = (int)sy; iy = iy < 0 ? 0 : (iy > rl - 2 ? rl - 2 : iy);
    int iz = (int)sz; iz = iz < 0 ? 0 : (iz > rl - 2 ? rl - 2 : iz);
    p.ix = ix; p.iy = iy; p.iz = iz;
    p.fx = sx - (float)ix; p.fy = sy - (float)iy; p.fz = sz - (float)iz;
    return p;
}

struct C8 { uint32_t c0, c1, c2, c3, c4, c5, c6, c7; };

// hash gather via aligned quads: h(x+1) = h(x) ^ (x^(x+1)); both x-corners in
// the same aligned 16B quad whenever ix%4 != 3 -> 4 dwordx4 req, +4 scalar in
// 25% of cases. Verified correct in round 4 (absmax 4.8e-7).
__device__ __forceinline__ C8 gather_hash(const uint32_t* __restrict__ t,
                                          const Pt& p) {
    const uint32_t hx = (uint32_t)p.ix;
    const uint32_t dx = hx ^ (hx + 1u);
    const uint32_t y0 = (uint32_t)p.iy * PRIME1, y1 = y0 + PRIME1;
    const uint32_t z0 = (uint32_t)p.iz * PRIME2, z1 = z0 + PRIME2;
    const uint32_t i00 = (hx ^ y0 ^ z0) & T_MASK;
    const uint32_t i10 = (hx ^ y1 ^ z0) & T_MASK;
    const uint32_t i01 = (hx ^ y0 ^ z1) & T_MASK;
    const uint32_t i11 = (hx ^ y1 ^ z1) & T_MASK;
    const uint4 q00 = *(const uint4*)(t + (i00 & ~3u));
    const uint4 q10 = *(const uint4*)(t + (i10 & ~3u));
    const uint4 q01 = *(const uint4*)(t + (i01 & ~3u));
    const uint4 q11 = *(const uint4*)(t + (i11 & ~3u));
    C8 r;
    if (dx < 4u) {           // second x-corner inside the same quad
        r.c1 = sel4(q00, (i00 ^ dx) & 3u);
        r.c3 = sel4(q10, (i10 ^ dx) & 3u);
        r.c5 = sel4(q01, (i01 ^ dx) & 3u);
        r.c7 = sel4(q11, (i11 ^ dx) & 3u);
    } else {                 // ix%4==3: quad doesn't cover ix+1
        r.c1 = t[(i00 ^ dx) & T_MASK];
        r.c3 = t[(i10 ^ dx) & T_MASK];
        r.c5 = t[(i01 ^ dx) & T_MASK];
        r.c7 = t[(i11 ^ dx) & T_MASK];
    }
    r.c0 = sel4(q00, i00 & 3u);
    r.c2 = sel4(q10, i10 & 3u);
    r.c4 = sel4(q01, i01 & 3u);
    r.c6 = sel4(q11, i11 & 3u);
    return r;
}

// cell gather (levels 0..4): all 8 corners contiguous, 2 dwordx4 req
__device__ __forceinline__ C8 gather_cell(const uint32_t* __restrict__ t,
                                          int C, const Pt& p) {
    const uint32_t* cb = t + (size_t)((p.iz * C + p.iy) * C + p.ix) * 8;
    const uint4 q0 = *(const uint4*)cb;
    const uint4 q1 = *(const uint4*)(cb + 4);
    C8 r;
    r.c0 = q0.x; r.c1 = q0.y; r.c2 = q0.z; r.c3 = q0.w;
    r.c4 = q1.x; r.c5 = q1.y; r.c6 = q1.z; r.c7 = q1.w;
    return r;
}

__device__ __forceinline__ float2 blend8(const C8& c, const Pt& p) {
    const float wx0 = 1.0f - p.fx, wx1 = p.fx;
    const float wy0 = 1.0f - p.fy, wy1 = p.fy;
    const float wz0 = 1.0f - p.fz, wz1 = p.fz;
    float w, f0 = 0.0f, f1 = 0.0f;
    w = wx0 * wy0 * wz0; f0 = fmaf(w, bf_lo(c.c0), f0); f1 = fmaf(w, bf_hi(c.c0), f1);
    w = wx1 * wy0 * wz0; f0 = fmaf(w, bf_lo(c.c1), f0); f1 = fmaf(w, bf_hi(c.c1), f1);
    w = wx0 * wy1 * wz0; f0 = fmaf(w, bf_lo(c.c2), f0); f1 = fmaf(w, bf_hi(c.c2), f1);
    w = wx1 * wy1 * wz0; f0 = fmaf(w, bf_lo(c.c3), f0); f1 = fmaf(w, bf_hi(c.c3), f1);
    w = wx0 * wy0 * wz1; f0 = fmaf(w, bf_lo(c.c4), f0); f1 = fmaf(w, bf_hi(c.c4), f1);
    w = wx1 * wy0 * wz1; f0 = fmaf(w, bf_lo(c.c5), f0); f1 = fmaf(w, bf_hi(c.c5), f1);
    w = wx0 * wy1 * wz1; f0 = fmaf(w, bf_lo(c.c6), f0); f1 = fmaf(w, bf_hi(c.c6), f1);
    w = wx1 * wy1 * wz1; f0 = fmaf(w, bf_lo(c.c7), f0); f1 = fmaf(w, bf_hi(c.c7), f1);
    float2 o; o.x = f0; o.y = f1;
    return o;
}

// ---------- phase 1: gather + trilinear blend, level-major output ----------
// Thread = 2 adjacent points x level pair (l, l+8). All tables L2-sized:
//   l<5 : cell table (<=3.1MB) + hash(l+8) 2MB  -> <=5.1MB per XCD
//   l>=5: hash(l) 2MB + hash(l+8) 2MB           -> 4MB per XCD
// Requests/point-level: cell 2, hash ~5 (quad-covered). No footprint blowup
// (round-4 lesson: pair tables for levels 6,7 overflowed L2 -> 3x FETCH).
__global__ __launch_bounds__(256, 4) void hg_levels(
    const float* __restrict__ x,
    const uint32_t* __restrict__ tabF,   // [11, T] packed bf16x2 (levels 5..15)
    const uint32_t* __restrict__ tabD,   // cell tables (levels 0..4)
    float2* __restrict__ feat,           // [16, N]
    int N, Params P)
{
    const int l  = blockIdx.x & 7;           // low level; high level = l+8
    const int lf = l + 8;
    const int tt = (blockIdx.x >> 3) * 256 + threadIdx.x;
    const int n0 = tt * 2;
    if (n0 >= N) return;
    const int n1 = n0 + 1;
    const bool hasB = (n1 < N);

    float ax, ay, az, bx, by, bz;
    const float* xb = x + (size_t)n0 * 3;
    if (hasB) {
        const float2 u0 = *(const float2*)(xb);
        const float2 u1 = *(const float2*)(xb + 2);
        const float2 u2 = *(const float2*)(xb + 4);
        ax = u0.x; ay = u0.y; az = u1.x; bx = u1.y; by = u2.x; bz = u2.y;
    } else {
        ax = xb[0]; ay = xb[1]; az = xb[2]; bx = ax; by = ay; bz = az;
    }

    const int rd = P.res[l];  const float rdf = (float)(rd - 1);
    const int rh = P.res[lf]; const float rhf = (float)(rh - 1);

    const Pt fA = mk_pt(ax, ay, az, rh, rhf);
    const Pt fB = mk_pt(bx, by, bz, rh, rhf);
    const Pt dA = mk_pt(ax, ay, az, rd, rdf);
    const Pt dB = mk_pt(bx, by, bz, rd, rdf);

    // high level (always hash)
    const uint32_t* __restrict__ tfF = tabF + (size_t)(lf - N_CELL) * T_SIZE;
    const C8 cfA = gather_hash(tfF, fA);
    const C8 cfB = gather_hash(tfF, fB);

    // low level: cell table for 0..4, hash for 5..7
    C8 cdA, cdB;
    if (l < N_CELL) {
        const uint32_t* __restrict__ td = tabD + P.dOff[l];
        const int C = rd - 1;
        cdA = gather_cell(td, C, dA);
        cdB = gather_cell(td, C, dB);
    } else {
        const uint32_t* __restrict__ tfD = tabF + (size_t)(l - N_CELL) * T_SIZE;
        cdA = gather_hash(tfD, dA);
        cdB = gather_hash(tfD, dB);
    }

    const float2 oFA = blend8(cfA, fA);
    const float2 oFB = blend8(cfB, fB);
    const float2 oDA = blend8(cdA, dA);
    const float2 oDB = blend8(cdB, dB);

    if (hasB) {
        f4v oD; oD.x = oDA.x; oD.y = oDA.y; oD.z = oDB.x; oD.w = oDB.y;
        __builtin_nontemporal_store(oD, (f4v*)&feat[(size_t)l * N + n0]);
        f4v oF; oF.x = oFA.x; oF.y = oFA.y; oF.z = oFB.x; oF.w = oFB.y;
        __builtin_nontemporal_store(oF, (f4v*)&feat[(size_t)lf * N + n0]);
    } else {
        nt_store_f2(oDA, &feat[(size_t)l  * N + n0]);
        nt_store_f2(oFA, &feat[(size_t)lf * N + n0]);
    }
}

// ---------- phase 2: LDS-tiled transpose [16,N] -> [N,16] ----------
// 128 points/block: reads are 1KB contiguous per level row (full-wave float4),
// writes 2KB contiguous. Old 32-pt version had 256B segments (~1.4 TB/s).
__global__ __launch_bounds__(256) void hg_transpose(
    const float2* __restrict__ feat, f4v* __restrict__ out, int N)
{
    __shared__ float2 st[N_LEVELS][131];   // pad 131: <=2-way banks both phases
    const int base = blockIdx.x * 128;
    const int t = threadIdx.x;
#pragma unroll
    for (int i = 0; i < 4; ++i) {
        const int idx = i * 256 + t;           // 0..1023
        const int l = idx >> 6, pp = (idx & 63) * 2;
        const int n = base + pp;
        float2 v0 = make_float2(0.f, 0.f), v1 = v0;
        if (n + 1 < N) {
            const f4v q = __builtin_nontemporal_load((const f4v*)&feat[(size_t)l * N + n]);
            v0.x = q.x; v0.y = q.y; v1.x = q.z; v1.y = q.w;
        } else if (n < N) {
            v0 = nt_load_f2(&feat[(size_t)l * N + n]);
        }
        st[l][pp] = v0; st[l][pp + 1] = v1;
    }
    __syncthreads();
#pragma unroll
    for (int i = 0; i < 4; ++i) {
        const int idx = i * 256 + t;           // 0..1023
        const int p = idx >> 3, k = idx & 7;
        const int n = base + p;
        if (n < N) {
            const float2 a = st[2 * k][p], b = st[2 * k + 1][p];
            f4v o; o.x = a.x; o.y = a.y; o.z = b.x; o.w = b.y;
            __builtin_nontemporal_store(o, &out[(size_t)n * 8 + k]);
        }
    }
}

// ---------- fallback: used only if ws is too small ----------
__global__ __launch_bounds__(256) void hg_fallback(
    const float* __restrict__ x, const float* __restrict__ emb,
    float* __restrict__ out, int N, Params P)
{
    const int gid = blockIdx.x * 256 + threadIdx.x;
    const int n = gid >> 4, l = gid & 15;
    if (n >= N) return;
    const int rl = P.res[l];
    const float rf = (float)(rl - 1);
    float sx = x[n * 3 + 0] * rf, sy = x[n * 3 + 1] * rf, sz = x[n * 3 + 2] * rf;
    int ix = (int)sx; ix = ix < 0 ? 0 : (ix > rl - 2 ? rl - 2 : ix);
    int iy = (int)sy; iy = iy < 0 ? 0 : (iy > rl - 2 ? rl - 2 : iy);
    int iz = (int)sz; iz = iz < 0 ? 0 : (iz > rl - 2 ? rl - 2 : iz);
    const float fx = sx - ix, fy = sy - iy, fz = sz - iz;
    const uint32_t hx0 = (uint32_t)ix, hx1 = hx0 + 1u;
    const uint32_t hy0 = (uint32_t)iy * PRIME1, hy1 = hy0 + PRIME1;
    const uint32_t hz0 = (uint32_t)iz * PRIME2, hz1 = hz0 + PRIME2;
    const float2* tab = (const float2*)emb + (size_t)l * T_SIZE;
    float2 e0 = tab[(hx0 ^ hy0 ^ hz0) & T_MASK], e1 = tab[(hx1 ^ hy0 ^ hz0) & T_MASK];
    float2 e2 = tab[(hx0 ^ hy1 ^ hz0) & T_MASK], e3 = tab[(hx1 ^ hy1 ^ hz0) & T_MASK];
    float2 e4 = tab[(hx0 ^ hy0 ^ hz1) & T_MASK], e5 = tab[(hx1 ^ hy0 ^ hz1) & T_MASK];
    float2 e6 = tab[(hx0 ^ hy1 ^ hz1) & T_MASK], e7 = tab[(hx1 ^ hy1 ^ hz1) & T_MASK];
    const float wx0 = 1.0f - fx, wx1 = fx, wy0 = 1.0f - fy, wy1 = fy, wz0 = 1.0f - fz, wz1 = fz;
    float w, f0 = 0.0f, f1 = 0.0f;
    w = wx0 * wy0 * wz0; f0 = fmaf(w, e0.x, f0); f1 = fmaf(w, e0.y, f1);
    w = wx1 * wy0 * wz0; f0 = fmaf(w, e1.x, f0); f1 = fmaf(w, e1.y, f1);
    w = wx0 * wy1 * wz0; f0 = fmaf(w, e2.x, f0); f1 = fmaf(w, e2.y, f1);
    w = wx1 * wy1 * wz0; f0 = fmaf(w, e3.x, f0); f1 = fmaf(w, e3.y, f1);
    w = wx0 * wy0 * wz1; f0 = fmaf(w, e4.x, f0); f1 = fmaf(w, e4.y, f1);
    w = wx1 * wy0 * wz1; f0 = fmaf(w, e5.x, f0); f1 = fmaf(w, e5.y, f1);
    w = wx0 * wy1 * wz1; f0 = fmaf(w, e6.x, f0); f1 = fmaf(w, e6.y, f1);
    w = wx1 * wy1 * wz1; f0 = fmaf(w, e7.x, f0); f1 = fmaf(w, e7.y, f1);
    float2 o; o.x = f0; o.y = f1;
    ((float2*)out)[(size_t)n * N_LEVELS + l] = o;
}

extern "C" void kernel_launch(void* const* d_in, const int* in_sizes, int n_in,
                              void* d_out, int out_size, void* d_ws, size_t ws_size,
                              hipStream_t stream) {
    const float* x   = (const float*)d_in[0];
    const float* emb = (const float*)d_in[1];
    const int N = in_sizes[0] / 3;

    // CPython-identical level resolutions (truncation-sensitive: 16*b^3 == 32)
    Params P;
    const double b = exp((log(512.0) - log(16.0)) / 15.0);
    for (int i = 0; i < N_LEVELS; ++i)
        P.res[i] = (int)(16.0 * pow(b, (double)i));

    // cell tables (levels 0..4)
    P.cellOffC[0] = 0;
    for (int l = 0; l < N_CELL; ++l) {
        const int C = P.res[l] - 1;
        P.cellOffC[l + 1] = P.cellOffC[l] + C * C * C;
    }
    P.cellTot = P.cellOffC[N_CELL];
    for (int l = 0; l < N_CELL; ++l) P.dOff[l] = P.cellOffC[l] * 8;

    const size_t fine_bytes  = (size_t)N_HASH * T_SIZE * sizeof(uint32_t);        // 22 MB
    const size_t dense_bytes = ((size_t)P.cellTot * 8 * sizeof(uint32_t) + 255) & ~255ull; // ~5.4 MB
    const size_t feat_bytes  = (size_t)N_LEVELS * N * sizeof(float2);             // 128 MB

    if (ws_size >= fine_bytes + dense_bytes + feat_bytes) {
        uint32_t* tabF = (uint32_t*)d_ws;
        uint32_t* tabD = (uint32_t*)((char*)d_ws + fine_bytes);
        float2*   feat = (float2*)((char*)d_ws + fine_bytes + dense_bytes);

        hipLaunchKernelGGL(hg_build_fine, dim3(N_HASH * T_SIZE / 256), dim3(256), 0, stream,
                           (const float2*)emb, tabF);
        hipLaunchKernelGGL(hg_build_cell, dim3((P.cellTot * 8 + 255) / 256), dim3(256), 0, stream,
                           (const float2*)emb, tabD, P);

        const int chunks = (N + 511) / 512;    // 512 points per block (2/thread)
        hipLaunchKernelGGL(hg_levels, dim3(chunks * 8), dim3(256), 0, stream,
                           x, tabF, tabD, feat, N, P);

        hipLaunchKernelGGL(hg_transpose, dim3((N + 127) / 128), dim3(256), 0, stream,
                           feat, (f4v*)d_out, N);
    } else {
        hipLaunchKernelGGL(hg_fallback, dim3((N * 16 + 255) / 256), dim3(256), 0, stream,
                           x, emb, (float*)d_out, N, P);
    }
}